// Round 8
// baseline (480.992 us; speedup 1.0000x reference)
//
#include <hip/hip_runtime.h>
#include <math.h>

#define NNODES 50000
#define NEDGES 800000
#define NTOT   850000   // edges + self-loops
#define NHEAD  8
#define HDIM   32
#define HHD    256      // NHEAD*HDIM
#define NCLS   40
#define NEG_SLOPE 0.2f

typedef _Float16 half4 __attribute__((ext_vector_type(4)));
typedef _Float16 half8 __attribute__((ext_vector_type(8)));
typedef float f32x16 __attribute__((ext_vector_type(16)));
typedef unsigned short u16;

// ---------------- CSR build ----------------

__global__ void k_init_counts(int* __restrict__ counts) {
    int i = blockIdx.x * 256 + threadIdx.x;
    if (i < NNODES) counts[i] = 1;   // self-loop
}

__global__ void k_count(const int* __restrict__ ei, int* __restrict__ counts) {
    int i = blockIdx.x * 256 + threadIdx.x;
    if (i < NEDGES) atomicAdd(&counts[ei[NEDGES + i]], 1);  // dst row
}

__global__ __launch_bounds__(256) void k_scan1(const int* __restrict__ counts,
                                               int* __restrict__ partial,
                                               int* __restrict__ bsums) {
    __shared__ int lds[256];
    int t = threadIdx.x;
    int i = blockIdx.x * 256 + t;
    int v = (i < NNODES) ? counts[i] : 0;
    lds[t] = v;
    __syncthreads();
    for (int off = 1; off < 256; off <<= 1) {
        int add = (t >= off) ? lds[t - off] : 0;
        __syncthreads();
        lds[t] += add;
        __syncthreads();
    }
    if (i < NNODES) partial[i] = lds[t] - v;   // exclusive within block
    if (t == 255) bsums[blockIdx.x] = lds[255];
}

__global__ __launch_bounds__(256) void k_scan2(const int* __restrict__ bsums,
                                               int* __restrict__ boff, int nb) {
    __shared__ int lds[256];
    int t = threadIdx.x;
    int v = (t < nb) ? bsums[t] : 0;
    lds[t] = v;
    __syncthreads();
    for (int off = 1; off < 256; off <<= 1) {
        int add = (t >= off) ? lds[t - off] : 0;
        __syncthreads();
        lds[t] += add;
        __syncthreads();
    }
    if (t < nb) boff[t] = lds[t] - v;
}

__global__ void k_scan3(int* __restrict__ row_ptr, const int* __restrict__ boff,
                        int* __restrict__ cursor) {
    int i = blockIdx.x * 256 + threadIdx.x;
    if (i < NNODES) {
        int r = row_ptr[i] + boff[blockIdx.x];
        row_ptr[i] = r;
        cursor[i] = r;
    }
    if (i == 0) row_ptr[NNODES] = NTOT;
}

// fused: regular edges + self-loops
__global__ void k_scatter(const int* __restrict__ ei, int* __restrict__ cursor,
                          int* __restrict__ esrc) {
    int i = blockIdx.x * 256 + threadIdx.x;
    if (i < NEDGES) {
        int s = ei[i];
        int d = ei[NEDGES + i];
        int pos = atomicAdd(&cursor[d], 1);
        esrc[pos] = s;
    } else if (i < NTOT) {
        int n = i - NEDGES;
        int pos = atomicAdd(&cursor[n], 1);
        esrc[pos] = n;
    }
}

// ---------------- weight prep: transpose + fp16 convert ----------------
// W[K,Nc] fp32 -> Wt [Npad][K] fp16 (k-contiguous rows)
__global__ void k_prep_w(const float* __restrict__ W, _Float16* __restrict__ Wt,
                         int K, int Nc, int Npad) {
    int idx = blockIdx.x * 256 + threadIdx.x;   // n*K + k
    if (idx >= Npad * K) return;
    int n = idx / K, k = idx - n * K;
    float w = (n < Nc) ? W[(size_t)k * Nc + n] : 0.f;
    Wt[idx] = (_Float16)w;
}

// ---------------- MFMA f16 GEMM (A: fp32 or fp16) ----------------
#define TBM 128
#define TBN 128
#define TBK 32
#define APAD 34   // 68 B row stride = 17 banks (odd) -> conflict-free b128

template <typename AT>
__global__ __launch_bounds__(256) void k_mfma_gemm(
    const AT* __restrict__ A,
    const _Float16* __restrict__ Wt,
    const float* __restrict__ bias,
    _Float16* __restrict__ Ch,
    float* __restrict__ Cf,
    int M, int K, int NcReal, int ldc)
{
    constexpr bool A_IS_F32 = sizeof(AT) == 4;
    __shared__ _Float16 Ah[TBM][APAD];
    int t = threadIdx.x;
    int lane = t & 63;
    int wid = t >> 6;
    int wr = wid >> 1, wc = wid & 1;            // 2x2 wave grid
    int rowBase = blockIdx.y * TBM;
    int colBase = blockIdx.x * TBN;

    int arow = t >> 1;
    int akoff = (t & 1) * 16;
    bool arow_ok = (rowBase + arow) < M;
    const AT* aptr = A + (size_t)(rowBase + arow) * K + akoff;

    f32x16 acc[2][2];
    #pragma unroll
    for (int i = 0; i < 2; ++i)
        #pragma unroll
        for (int j = 0; j < 2; ++j)
            #pragma unroll
            for (int r = 0; r < 16; ++r) acc[i][j][r] = 0.f;

    float4 aregf[4];
    half8  aregh[2];
    auto load_a = [&](const AT* ap) {
        if constexpr (A_IS_F32) {
            #pragma unroll
            for (int i = 0; i < 4; ++i)
                aregf[i] = arow_ok ? *reinterpret_cast<const float4*>((const float*)ap + i * 4)
                                   : float4{0.f, 0.f, 0.f, 0.f};
        } else {
            #pragma unroll
            for (int i = 0; i < 2; ++i)
                aregh[i] = arow_ok ? *reinterpret_cast<const half8*>((const _Float16*)ap + i * 8)
                                   : half8{0, 0, 0, 0, 0, 0, 0, 0};
        }
    };
    load_a(aptr);

    for (int k0 = 0; k0 < K; k0 += TBK) {
        if constexpr (A_IS_F32) {
            half8 h0, h1;
            #pragma unroll
            for (int c = 0; c < 4; ++c) {
                float4 v = aregf[c];
                if (c < 2) {
                    h0[c * 4 + 0] = (_Float16)v.x; h0[c * 4 + 1] = (_Float16)v.y;
                    h0[c * 4 + 2] = (_Float16)v.z; h0[c * 4 + 3] = (_Float16)v.w;
                } else {
                    h1[(c - 2) * 4 + 0] = (_Float16)v.x; h1[(c - 2) * 4 + 1] = (_Float16)v.y;
                    h1[(c - 2) * 4 + 2] = (_Float16)v.z; h1[(c - 2) * 4 + 3] = (_Float16)v.w;
                }
            }
            *reinterpret_cast<half8*>(&Ah[arow][akoff])     = h0;
            *reinterpret_cast<half8*>(&Ah[arow][akoff + 8]) = h1;
        } else {
            *reinterpret_cast<half8*>(&Ah[arow][akoff])     = aregh[0];
            *reinterpret_cast<half8*>(&Ah[arow][akoff + 8]) = aregh[1];
        }
        __syncthreads();
        if (k0 + TBK < K) load_a(aptr + k0 + TBK);
        #pragma unroll
        for (int sub = 0; sub < 2; ++sub) {
            int kfo = sub * 16 + (lane >> 5) * 8;
            half8 ah[2];
            #pragma unroll
            for (int rt = 0; rt < 2; ++rt) {
                int r = wr * 64 + rt * 32 + (lane & 31);
                ah[rt] = *reinterpret_cast<const half8*>(&Ah[r][kfo]);
            }
            half8 bh[2];
            #pragma unroll
            for (int ct = 0; ct < 2; ++ct) {
                int n = colBase + wc * 64 + ct * 32 + (lane & 31);
                bh[ct] = *reinterpret_cast<const half8*>(Wt + (size_t)n * K + k0 + kfo);
            }
            #pragma unroll
            for (int rt = 0; rt < 2; ++rt)
                #pragma unroll
                for (int ct = 0; ct < 2; ++ct)
                    acc[rt][ct] = __builtin_amdgcn_mfma_f32_32x32x16_f16(
                        ah[rt], bh[ct], acc[rt][ct], 0, 0, 0);
        }
        __syncthreads();
    }

    #pragma unroll
    for (int rt = 0; rt < 2; ++rt)
        #pragma unroll
        for (int ct = 0; ct < 2; ++ct) {
            int col = colBase + wc * 64 + ct * 32 + (lane & 31);
            #pragma unroll
            for (int r = 0; r < 16; ++r) {
                int row = rowBase + wr * 64 + rt * 32 +
                          (r & 3) + 8 * (r >> 2) + 4 * (lane >> 5);
                if (row >= M) continue;
                float v = acc[rt][ct][r];
                if (Ch) {
                    Ch[(size_t)row * ldc + col] = (_Float16)v;
                } else if (col < NcReal) {
                    Cf[(size_t)row * ldc + col] = v + bias[col];
                }
            }
        }
}

// ---------------- per-node attention coefficients (fp16 features) ----------
__global__ void k_alpha(const _Float16* __restrict__ xh,
                        const float* __restrict__ a_src,
                        const float* __restrict__ a_dst,
                        float* __restrict__ alpha_s,
                        float* __restrict__ alpha_d) {
    int idx = blockIdx.x * 256 + threadIdx.x;   // n*8 + h
    if (idx >= NNODES * NHEAD) return;
    int node = idx >> 3, h = idx & 7;
    const half4* p  = reinterpret_cast<const half4*>(xh + (size_t)node * HHD + h * HDIM);
    const float4* ps = reinterpret_cast<const float4*>(a_src + h * HDIM);
    const float4* pd = reinterpret_cast<const float4*>(a_dst + h * HDIM);
    float ss = 0.f, sd = 0.f;
    #pragma unroll
    for (int q = 0; q < 8; ++q) {
        half4 hv = p[q];
        float4 s4 = ps[q], d4 = pd[q];
        float vx = (float)hv.x, vy = (float)hv.y, vz = (float)hv.z, vw = (float)hv.w;
        ss += vx * s4.x + vy * s4.y + vz * s4.z + vw * s4.w;
        sd += vx * d4.x + vy * d4.y + vz * d4.z + vw * d4.w;
    }
    alpha_s[idx] = ss;
    alpha_d[idx] = sd;
}

// ---------------- GAT aggregation: head-sliced, XCD-affine ----------------
// slice = blockIdx.x & 7 -> one head (32 dims, 64 B/row). Consecutive blockIdx
// round-robin across the 8 XCDs, so each XCD's L2 holds only its slice of xh
// (3.2 MB) + alpha_s (1.6 MB) -> random gathers become L2 hits.
// 4 lanes per node (8 dims each), 16 nodes per wave. Per-edge math identical
// to the unsliced version (p/exp already replicated per lane) -> bit-identical.
__global__ __launch_bounds__(256) void k_agg(const _Float16* __restrict__ xh,
                                             const float* __restrict__ alpha_s,
                                             const float* __restrict__ alpha_d,
                                             const int* __restrict__ row_ptr,
                                             const int* __restrict__ esrc,
                                             const float* __restrict__ bias,
                                             _Float16* __restrict__ out) {
    int slice = blockIdx.x & 7;                     // == head; pins to one XCD
    int node  = (blockIdx.x >> 3) * 64 + (threadIdx.x >> 2);
    if (node >= NNODES) return;
    int q = threadIdx.x & 3;
    int h = slice;
    int dbase = slice * 32 + q * 8;                 // this lane's 8 dims
    int beg = row_ptr[node], end = row_ptr[node + 1];
    float ad = alpha_d[node * NHEAD + h];
    float acc[8] = {};
    float ssum = 0.f;
    int i = beg;
    for (; i + 3 < end; i += 4) {
        int s0 = esrc[i], s1 = esrc[i + 1], s2 = esrc[i + 2], s3 = esrc[i + 3];
        float e0 = alpha_s[s0 * NHEAD + h] + ad;
        float e1 = alpha_s[s1 * NHEAD + h] + ad;
        float e2 = alpha_s[s2 * NHEAD + h] + ad;
        float e3 = alpha_s[s3 * NHEAD + h] + ad;
        half8 v0 = *reinterpret_cast<const half8*>(xh + (size_t)s0 * HHD + dbase);
        half8 v1 = *reinterpret_cast<const half8*>(xh + (size_t)s1 * HHD + dbase);
        half8 v2 = *reinterpret_cast<const half8*>(xh + (size_t)s2 * HHD + dbase);
        half8 v3 = *reinterpret_cast<const half8*>(xh + (size_t)s3 * HHD + dbase);
        e0 = (e0 > 0.f) ? e0 : NEG_SLOPE * e0;
        e1 = (e1 > 0.f) ? e1 : NEG_SLOPE * e1;
        e2 = (e2 > 0.f) ? e2 : NEG_SLOPE * e2;
        e3 = (e3 > 0.f) ? e3 : NEG_SLOPE * e3;
        float p0 = __expf(e0), p1 = __expf(e1), p2 = __expf(e2), p3 = __expf(e3);
        ssum += (p0 + p1) + (p2 + p3);
        #pragma unroll
        for (int d = 0; d < 8; ++d)
            acc[d] += p0 * (float)v0[d] + p1 * (float)v1[d] +
                      p2 * (float)v2[d] + p3 * (float)v3[d];
    }
    for (; i < end; ++i) {
        int s0 = esrc[i];
        float e0 = alpha_s[s0 * NHEAD + h] + ad;
        half8 v0 = *reinterpret_cast<const half8*>(xh + (size_t)s0 * HHD + dbase);
        e0 = (e0 > 0.f) ? e0 : NEG_SLOPE * e0;
        float p0 = __expf(e0);
        ssum += p0;
        #pragma unroll
        for (int d = 0; d < 8; ++d)
            acc[d] += p0 * (float)v0[d];
    }
    float inv = 1.f / ssum;
    float4 b0 = *reinterpret_cast<const float4*>(bias + dbase);
    float4 b1 = *reinterpret_cast<const float4*>(bias + dbase + 4);
    float bb[8] = {b0.x, b0.y, b0.z, b0.w, b1.x, b1.y, b1.z, b1.w};
    half8 r;
    #pragma unroll
    for (int d = 0; d < 8; ++d)
        r[d] = (_Float16)fmaxf(acc[d] * inv + bb[d], 0.f);
    *reinterpret_cast<half8*>(out + (size_t)node * HHD + dbase) = r;
}

// ---------------- launch ----------------

extern "C" void kernel_launch(void* const* d_in, const int* in_sizes, int n_in,
                              void* d_out, int out_size, void* d_ws, size_t ws_size,
                              hipStream_t stream) {
    const float* x   = (const float*)d_in[0];
    const int*   ei  = (const int*)  d_in[1];
    const float* W1  = (const float*)d_in[2];
    const float* a1s = (const float*)d_in[3];
    const float* a1d = (const float*)d_in[4];
    const float* b1  = (const float*)d_in[5];
    const float* W2  = (const float*)d_in[6];
    const float* a2s = (const float*)d_in[7];
    const float* a2d = (const float*)d_in[8];
    const float* b2  = (const float*)d_in[9];
    const float* Wc  = (const float*)d_in[10];
    const float* bc  = (const float*)d_in[11];
    float* out = (float*)d_out;

    char* ws = (char*)d_ws;
    size_t off = 0;
    auto alloc = [&](size_t bytes) -> void* {
        void* p = ws + off;
        off += (bytes + 255) & ~(size_t)255;
        return p;
    };
    _Float16* xh_h   = (_Float16*)alloc((size_t)NNODES * HHD * 2);
    _Float16* hbuf_h = (_Float16*)alloc((size_t)NNODES * HHD * 2);
    float* as_   = (float*)alloc((size_t)NNODES * NHEAD * 4);
    float* ad_   = (float*)alloc((size_t)NNODES * NHEAD * 4);
    int* counts  = (int*)alloc((size_t)NNODES * 4);
    int* row_ptr = (int*)alloc((size_t)(NNODES + 1) * 4);
    int* cursor  = (int*)alloc((size_t)NNODES * 4);
    int* esrc    = (int*)alloc((size_t)NTOT * 4);
    int* bsums   = (int*)alloc(256 * 4);
    int* boff    = (int*)alloc(256 * 4);
    _Float16* w1t = (_Float16*)alloc((size_t)HHD * 128 * 2);   // [256][128]
    _Float16* w2t = (_Float16*)alloc((size_t)HHD * HHD * 2);   // [256][256]
    _Float16* wct = (_Float16*)alloc((size_t)TBN * HHD * 2);   // [128][256] padded
    (void)ws_size; (void)in_sizes; (void)n_in; (void)out_size;

    int gn = (NNODES + 255) / 256;
    int ge = (NEDGES + 255) / 256;
    int gt = (NTOT + 255) / 256;

    // CSR build (same graph for both layers)
    k_init_counts<<<gn, 256, 0, stream>>>(counts);
    k_count<<<ge, 256, 0, stream>>>(ei, counts);
    k_scan1<<<gn, 256, 0, stream>>>(counts, row_ptr, bsums);
    k_scan2<<<1, 256, 0, stream>>>(bsums, boff, gn);
    k_scan3<<<gn, 256, 0, stream>>>(row_ptr, boff, cursor);
    k_scatter<<<gt, 256, 0, stream>>>(ei, cursor, esrc);

    // weight prep (transpose + fp16)
    k_prep_w<<<(HHD * 128 + 255) / 256, 256, 0, stream>>>(W1, w1t, 128, HHD, HHD);
    k_prep_w<<<(HHD * HHD + 255) / 256, 256, 0, stream>>>(W2, w2t, HHD, HHD, HHD);
    k_prep_w<<<(TBN * HHD + 255) / 256, 256, 0, stream>>>(Wc, wct, HHD, NCLS, TBN);

    dim3 gHid(HHD / TBN, (NNODES + TBM - 1) / TBM);   // (2, 391)
    dim3 gCls(1, (NNODES + TBM - 1) / TBM);           // (1, 391)
    int ga = (NNODES * NHEAD + 255) / 256;
    int gagg = ((NNODES + 63) / 64) * 8;              // 782 node-groups x 8 slices

    // layer 1
    k_mfma_gemm<float><<<gHid, 256, 0, stream>>>(x, w1t, nullptr, xh_h, nullptr,
                                                 NNODES, 128, HHD, HHD);
    k_alpha<<<ga, 256, 0, stream>>>(xh_h, a1s, a1d, as_, ad_);
    k_agg<<<gagg, 256, 0, stream>>>(xh_h, as_, ad_, row_ptr, esrc, b1, hbuf_h);

    // layer 2
    k_mfma_gemm<_Float16><<<gHid, 256, 0, stream>>>(hbuf_h, w2t, nullptr, xh_h, nullptr,
                                                    NNODES, HHD, HHD, HHD);
    k_alpha<<<ga, 256, 0, stream>>>(xh_h, a2s, a2d, as_, ad_);
    k_agg<<<gagg, 256, 0, stream>>>(xh_h, as_, ad_, row_ptr, esrc, b2, hbuf_h);

    // classifier
    k_mfma_gemm<_Float16><<<gCls, 256, 0, stream>>>(hbuf_h, wct, bc, nullptr, out,
                                                    NNODES, HHD, NCLS, NCLS);
}

// Round 9
// 349.389 us; speedup vs baseline: 1.3767x; 1.3767x over previous
//
#include <hip/hip_runtime.h>
#include <math.h>

#define NNODES 50000
#define NEDGES 800000
#define NTOT   850000   // edges + self-loops
#define NHEAD  8
#define HDIM   32
#define HHD    256      // NHEAD*HDIM
#define NCLS   40
#define NEG_SLOPE 0.2f

typedef _Float16 half4 __attribute__((ext_vector_type(4)));
typedef _Float16 half8 __attribute__((ext_vector_type(8)));
typedef float f32x16 __attribute__((ext_vector_type(16)));
typedef unsigned short u16;

// ---------------- CSR build ----------------

__global__ void k_init_counts(int* __restrict__ counts) {
    int i = blockIdx.x * 256 + threadIdx.x;
    if (i < NNODES) counts[i] = 1;   // self-loop
}

__global__ void k_count(const int* __restrict__ ei, int* __restrict__ counts) {
    int i = blockIdx.x * 256 + threadIdx.x;
    if (i < NEDGES) atomicAdd(&counts[ei[NEDGES + i]], 1);  // dst row
}

__global__ __launch_bounds__(256) void k_scan1(const int* __restrict__ counts,
                                               int* __restrict__ partial,
                                               int* __restrict__ bsums) {
    __shared__ int lds[256];
    int t = threadIdx.x;
    int i = blockIdx.x * 256 + t;
    int v = (i < NNODES) ? counts[i] : 0;
    lds[t] = v;
    __syncthreads();
    for (int off = 1; off < 256; off <<= 1) {
        int add = (t >= off) ? lds[t - off] : 0;
        __syncthreads();
        lds[t] += add;
        __syncthreads();
    }
    if (i < NNODES) partial[i] = lds[t] - v;   // exclusive within block
    if (t == 255) bsums[blockIdx.x] = lds[255];
}

__global__ __launch_bounds__(256) void k_scan2(const int* __restrict__ bsums,
                                               int* __restrict__ boff, int nb) {
    __shared__ int lds[256];
    int t = threadIdx.x;
    int v = (t < nb) ? bsums[t] : 0;
    lds[t] = v;
    __syncthreads();
    for (int off = 1; off < 256; off <<= 1) {
        int add = (t >= off) ? lds[t - off] : 0;
        __syncthreads();
        lds[t] += add;
        __syncthreads();
    }
    if (t < nb) boff[t] = lds[t] - v;
}

__global__ void k_scan3(int* __restrict__ row_ptr, const int* __restrict__ boff,
                        int* __restrict__ cursor) {
    int i = blockIdx.x * 256 + threadIdx.x;
    if (i < NNODES) {
        int r = row_ptr[i] + boff[blockIdx.x];
        row_ptr[i] = r;
        cursor[i] = r;
    }
    if (i == 0) row_ptr[NNODES] = NTOT;
}

// fused: regular edges + self-loops
__global__ void k_scatter(const int* __restrict__ ei, int* __restrict__ cursor,
                          int* __restrict__ esrc) {
    int i = blockIdx.x * 256 + threadIdx.x;
    if (i < NEDGES) {
        int s = ei[i];
        int d = ei[NEDGES + i];
        int pos = atomicAdd(&cursor[d], 1);
        esrc[pos] = s;
    } else if (i < NTOT) {
        int n = i - NEDGES;
        int pos = atomicAdd(&cursor[n], 1);
        esrc[pos] = n;
    }
}

// ---------------- weight prep: MFMA fragment layout ----------------
// W[K,Nc] fp32 -> Wt fragment-packed fp16:
//   frag_id = fn*(K/16)+fk (fn=n>>5, fk=k>>4); within frag, lane l =
//   ((k>>3)&1)<<5 | (n&31) holds 8 halves (k&7). One wave's half8 load of a
//   frag is 1 KB CONTIGUOUS -> fully coalesced B reads in the GEMM.
__global__ void k_prep_wfrag(const float* __restrict__ W, _Float16* __restrict__ Wt,
                             int K, int Nc, int nfrag) {
    int gid = blockIdx.x * 256 + threadIdx.x;
    if (gid >= nfrag * 64) return;
    int frag = gid >> 6, l = gid & 63;
    int fkn = K >> 4;
    int fn = frag / fkn, fk = frag - fn * fkn;
    int n = fn * 32 + (l & 31);
    int k = fk * 16 + ((l >> 5) << 3);
    half8 v;
    #pragma unroll
    for (int j = 0; j < 8; ++j)
        v[j] = (n < Nc) ? (_Float16)W[(size_t)(k + j) * Nc + n] : (_Float16)0.f;
    *reinterpret_cast<half8*>(Wt + (size_t)gid * 8) = v;
}

// ---------------- MFMA f16 GEMM (A: fp32 or fp16; B: fragment-packed) ------
#define TBM 128
#define TBN 128
#define TBK 32
#define APAD 34   // 68 B row stride = 17 banks (odd) -> conflict-free b128

template <typename AT>
__global__ __launch_bounds__(256) void k_mfma_gemm(
    const AT* __restrict__ A,
    const _Float16* __restrict__ Wt,   // fragment-packed
    const float* __restrict__ bias,
    _Float16* __restrict__ Ch,
    float* __restrict__ Cf,
    int M, int K, int NcReal, int ldc)
{
    constexpr bool A_IS_F32 = sizeof(AT) == 4;
    __shared__ _Float16 Ah[TBM][APAD];
    int t = threadIdx.x;
    int lane = t & 63;
    int wid = t >> 6;
    int wr = wid >> 1, wc = wid & 1;            // 2x2 wave grid
    int rowBase = blockIdx.y * TBM;
    int colBase = blockIdx.x * TBN;

    int arow = t >> 1;
    int akoff = (t & 1) * 16;
    bool arow_ok = (rowBase + arow) < M;
    const AT* aptr = A + (size_t)(rowBase + arow) * K + akoff;

    int fkn = K >> 4;   // frags per n-tile row
    // per-ct fragment base (halves): (fn*fkn)*512 + lane*8
    size_t bbase[2];
    #pragma unroll
    for (int ct = 0; ct < 2; ++ct) {
        int fn = blockIdx.x * 4 + wc * 2 + ct;
        bbase[ct] = ((size_t)fn * fkn) * 512 + (size_t)lane * 8;
    }

    f32x16 acc[2][2];
    #pragma unroll
    for (int i = 0; i < 2; ++i)
        #pragma unroll
        for (int j = 0; j < 2; ++j)
            #pragma unroll
            for (int r = 0; r < 16; ++r) acc[i][j][r] = 0.f;

    float4 aregf[4];
    half8  aregh[2];
    auto load_a = [&](const AT* ap) {
        if constexpr (A_IS_F32) {
            #pragma unroll
            for (int i = 0; i < 4; ++i)
                aregf[i] = arow_ok ? *reinterpret_cast<const float4*>((const float*)ap + i * 4)
                                   : float4{0.f, 0.f, 0.f, 0.f};
        } else {
            #pragma unroll
            for (int i = 0; i < 2; ++i)
                aregh[i] = arow_ok ? *reinterpret_cast<const half8*>((const _Float16*)ap + i * 8)
                                   : half8{0, 0, 0, 0, 0, 0, 0, 0};
        }
    };
    load_a(aptr);

    for (int k0 = 0; k0 < K; k0 += TBK) {
        if constexpr (A_IS_F32) {
            half8 h0, h1;
            #pragma unroll
            for (int c = 0; c < 4; ++c) {
                float4 v = aregf[c];
                if (c < 2) {
                    h0[c * 4 + 0] = (_Float16)v.x; h0[c * 4 + 1] = (_Float16)v.y;
                    h0[c * 4 + 2] = (_Float16)v.z; h0[c * 4 + 3] = (_Float16)v.w;
                } else {
                    h1[(c - 2) * 4 + 0] = (_Float16)v.x; h1[(c - 2) * 4 + 1] = (_Float16)v.y;
                    h1[(c - 2) * 4 + 2] = (_Float16)v.z; h1[(c - 2) * 4 + 3] = (_Float16)v.w;
                }
            }
            *reinterpret_cast<half8*>(&Ah[arow][akoff])     = h0;
            *reinterpret_cast<half8*>(&Ah[arow][akoff + 8]) = h1;
        } else {
            *reinterpret_cast<half8*>(&Ah[arow][akoff])     = aregh[0];
            *reinterpret_cast<half8*>(&Ah[arow][akoff + 8]) = aregh[1];
        }
        __syncthreads();
        if (k0 + TBK < K) load_a(aptr + k0 + TBK);
        #pragma unroll
        for (int sub = 0; sub < 2; ++sub) {
            int kfo = sub * 16 + (lane >> 5) * 8;
            half8 ah[2];
            #pragma unroll
            for (int rt = 0; rt < 2; ++rt) {
                int r = wr * 64 + rt * 32 + (lane & 31);
                ah[rt] = *reinterpret_cast<const half8*>(&Ah[r][kfo]);
            }
            half8 bh[2];
            int fidx = (k0 >> 4) + sub;            // fragment k index
            #pragma unroll
            for (int ct = 0; ct < 2; ++ct)
                bh[ct] = *reinterpret_cast<const half8*>(Wt + bbase[ct] + (size_t)fidx * 512);
            #pragma unroll
            for (int rt = 0; rt < 2; ++rt)
                #pragma unroll
                for (int ct = 0; ct < 2; ++ct)
                    acc[rt][ct] = __builtin_amdgcn_mfma_f32_32x32x16_f16(
                        ah[rt], bh[ct], acc[rt][ct], 0, 0, 0);
        }
        __syncthreads();
    }

    #pragma unroll
    for (int rt = 0; rt < 2; ++rt)
        #pragma unroll
        for (int ct = 0; ct < 2; ++ct) {
            int col = colBase + wc * 64 + ct * 32 + (lane & 31);
            #pragma unroll
            for (int r = 0; r < 16; ++r) {
                int row = rowBase + wr * 64 + rt * 32 +
                          (r & 3) + 8 * (r >> 2) + 4 * (lane >> 5);
                if (row >= M) continue;
                float v = acc[rt][ct][r];
                if (Ch) {
                    Ch[(size_t)row * ldc + col] = (_Float16)v;
                } else if (col < NcReal) {
                    Cf[(size_t)row * ldc + col] = v + bias[col];
                }
            }
        }
}

// ---------------- per-node attention coefficients (fp16 features) ----------
__global__ void k_alpha(const _Float16* __restrict__ xh,
                        const float* __restrict__ a_src,
                        const float* __restrict__ a_dst,
                        float* __restrict__ alpha_s,
                        float* __restrict__ alpha_d) {
    int idx = blockIdx.x * 256 + threadIdx.x;   // n*8 + h
    if (idx >= NNODES * NHEAD) return;
    int node = idx >> 3, h = idx & 7;
    const half4* p  = reinterpret_cast<const half4*>(xh + (size_t)node * HHD + h * HDIM);
    const float4* ps = reinterpret_cast<const float4*>(a_src + h * HDIM);
    const float4* pd = reinterpret_cast<const float4*>(a_dst + h * HDIM);
    float ss = 0.f, sd = 0.f;
    #pragma unroll
    for (int q = 0; q < 8; ++q) {
        half4 hv = p[q];
        float4 s4 = ps[q], d4 = pd[q];
        float vx = (float)hv.x, vy = (float)hv.y, vz = (float)hv.z, vw = (float)hv.w;
        ss += vx * s4.x + vy * s4.y + vz * s4.z + vw * s4.w;
        sd += vx * d4.x + vy * d4.y + vz * d4.z + vw * d4.w;
    }
    alpha_s[idx] = ss;
    alpha_d[idx] = sd;
}

// ---------------- GAT aggregation: fused single-pass softmax + gather ------
// (R6 structure: 2 nodes per wave, 32 lanes/node, full 512 B rows.)
// 8-way unroll for memory-level parallelism; 4-way and scalar tails.
__global__ __launch_bounds__(256) void k_agg(const _Float16* __restrict__ xh,
                                             const float* __restrict__ alpha_s,
                                             const float* __restrict__ alpha_d,
                                             const int* __restrict__ row_ptr,
                                             const int* __restrict__ esrc,
                                             const float* __restrict__ bias,
                                             _Float16* __restrict__ out) {
    int wave = blockIdx.x * 4 + (threadIdx.x >> 6);
    int node = wave * 2 + ((threadIdx.x & 63) >> 5);
    if (node >= NNODES) return;
    int l = threadIdx.x & 31;        // dim chunk [8l, 8l+8)
    int h = l >> 2;                  // head of this chunk
    int beg = row_ptr[node], end = row_ptr[node + 1];
    float ad = alpha_d[node * NHEAD + h];
    float acc[8] = {};
    float ssum = 0.f;
    int i = beg;
    for (; i + 7 < end; i += 8) {
        int s[8];
        #pragma unroll
        for (int u = 0; u < 8; ++u) s[u] = esrc[i + u];
        float e[8];
        #pragma unroll
        for (int u = 0; u < 8; ++u) e[u] = alpha_s[s[u] * NHEAD + h] + ad;
        half8 v[8];
        #pragma unroll
        for (int u = 0; u < 8; ++u)
            v[u] = *reinterpret_cast<const half8*>(xh + (size_t)s[u] * HHD + l * 8);
        float p[8];
        #pragma unroll
        for (int u = 0; u < 8; ++u) {
            float eu = (e[u] > 0.f) ? e[u] : NEG_SLOPE * e[u];
            p[u] = __expf(eu);
            ssum += p[u];
        }
        #pragma unroll
        for (int d = 0; d < 8; ++d) {
            float a = acc[d];
            #pragma unroll
            for (int u = 0; u < 8; ++u) a += p[u] * (float)v[u][d];
            acc[d] = a;
        }
    }
    for (; i + 3 < end; i += 4) {
        int s0 = esrc[i], s1 = esrc[i + 1], s2 = esrc[i + 2], s3 = esrc[i + 3];
        float e0 = alpha_s[s0 * NHEAD + h] + ad;
        float e1 = alpha_s[s1 * NHEAD + h] + ad;
        float e2 = alpha_s[s2 * NHEAD + h] + ad;
        float e3 = alpha_s[s3 * NHEAD + h] + ad;
        half8 v0 = *reinterpret_cast<const half8*>(xh + (size_t)s0 * HHD + l * 8);
        half8 v1 = *reinterpret_cast<const half8*>(xh + (size_t)s1 * HHD + l * 8);
        half8 v2 = *reinterpret_cast<const half8*>(xh + (size_t)s2 * HHD + l * 8);
        half8 v3 = *reinterpret_cast<const half8*>(xh + (size_t)s3 * HHD + l * 8);
        e0 = (e0 > 0.f) ? e0 : NEG_SLOPE * e0;
        e1 = (e1 > 0.f) ? e1 : NEG_SLOPE * e1;
        e2 = (e2 > 0.f) ? e2 : NEG_SLOPE * e2;
        e3 = (e3 > 0.f) ? e3 : NEG_SLOPE * e3;
        float p0 = __expf(e0), p1 = __expf(e1), p2 = __expf(e2), p3 = __expf(e3);
        ssum += (p0 + p1) + (p2 + p3);
        #pragma unroll
        for (int d = 0; d < 8; ++d)
            acc[d] += p0 * (float)v0[d] + p1 * (float)v1[d] +
                      p2 * (float)v2[d] + p3 * (float)v3[d];
    }
    for (; i < end; ++i) {
        int s0 = esrc[i];
        float e0 = alpha_s[s0 * NHEAD + h] + ad;
        half8 v0 = *reinterpret_cast<const half8*>(xh + (size_t)s0 * HHD + l * 8);
        e0 = (e0 > 0.f) ? e0 : NEG_SLOPE * e0;
        float p0 = __expf(e0);
        ssum += p0;
        #pragma unroll
        for (int d = 0; d < 8; ++d)
            acc[d] += p0 * (float)v0[d];
    }
    float inv = 1.f / ssum;
    float4 b0 = *reinterpret_cast<const float4*>(bias + l * 8);
    float4 b1 = *reinterpret_cast<const float4*>(bias + l * 8 + 4);
    float bb[8] = {b0.x, b0.y, b0.z, b0.w, b1.x, b1.y, b1.z, b1.w};
    half8 r;
    #pragma unroll
    for (int d = 0; d < 8; ++d)
        r[d] = (_Float16)fmaxf(acc[d] * inv + bb[d], 0.f);
    *reinterpret_cast<half8*>(out + (size_t)node * HHD + l * 8) = r;
}

// ---------------- launch ----------------

extern "C" void kernel_launch(void* const* d_in, const int* in_sizes, int n_in,
                              void* d_out, int out_size, void* d_ws, size_t ws_size,
                              hipStream_t stream) {
    const float* x   = (const float*)d_in[0];
    const int*   ei  = (const int*)  d_in[1];
    const float* W1  = (const float*)d_in[2];
    const float* a1s = (const float*)d_in[3];
    const float* a1d = (const float*)d_in[4];
    const float* b1  = (const float*)d_in[5];
    const float* W2  = (const float*)d_in[6];
    const float* a2s = (const float*)d_in[7];
    const float* a2d = (const float*)d_in[8];
    const float* b2  = (const float*)d_in[9];
    const float* Wc  = (const float*)d_in[10];
    const float* bc  = (const float*)d_in[11];
    float* out = (float*)d_out;

    char* ws = (char*)d_ws;
    size_t off = 0;
    auto alloc = [&](size_t bytes) -> void* {
        void* p = ws + off;
        off += (bytes + 255) & ~(size_t)255;
        return p;
    };
    _Float16* xh_h   = (_Float16*)alloc((size_t)NNODES * HHD * 2);
    _Float16* hbuf_h = (_Float16*)alloc((size_t)NNODES * HHD * 2);
    float* as_   = (float*)alloc((size_t)NNODES * NHEAD * 4);
    float* ad_   = (float*)alloc((size_t)NNODES * NHEAD * 4);
    int* counts  = (int*)alloc((size_t)NNODES * 4);
    int* row_ptr = (int*)alloc((size_t)(NNODES + 1) * 4);
    int* cursor  = (int*)alloc((size_t)NNODES * 4);
    int* esrc    = (int*)alloc((size_t)NTOT * 4);
    int* bsums   = (int*)alloc(256 * 4);
    int* boff    = (int*)alloc(256 * 4);
    _Float16* w1t = (_Float16*)alloc((size_t)HHD * 128 * 2);   // 64 frags
    _Float16* w2t = (_Float16*)alloc((size_t)HHD * HHD * 2);   // 128 frags
    _Float16* wct = (_Float16*)alloc((size_t)TBN * HHD * 2);   // 64 frags
    (void)ws_size; (void)in_sizes; (void)n_in; (void)out_size;

    int gn = (NNODES + 255) / 256;
    int ge = (NEDGES + 255) / 256;
    int gt = (NTOT + 255) / 256;

    // CSR build (same graph for both layers)
    k_init_counts<<<gn, 256, 0, stream>>>(counts);
    k_count<<<ge, 256, 0, stream>>>(ei, counts);
    k_scan1<<<gn, 256, 0, stream>>>(counts, row_ptr, bsums);
    k_scan2<<<1, 256, 0, stream>>>(bsums, boff, gn);
    k_scan3<<<gn, 256, 0, stream>>>(row_ptr, boff, cursor);
    k_scatter<<<gt, 256, 0, stream>>>(ei, cursor, esrc);

    // weight prep (fragment pack)
    k_prep_wfrag<<<(64 * 64 + 255) / 256, 256, 0, stream>>>(W1, w1t, 128, HHD, 64);
    k_prep_wfrag<<<(128 * 64 + 255) / 256, 256, 0, stream>>>(W2, w2t, HHD, HHD, 128);
    k_prep_wfrag<<<(64 * 64 + 255) / 256, 256, 0, stream>>>(Wc, wct, HHD, NCLS, 64);

    dim3 gHid(HHD / TBN, (NNODES + TBM - 1) / TBM);   // (2, 391)
    dim3 gCls(1, (NNODES + TBM - 1) / TBM);           // (1, 391)
    int ga = (NNODES * NHEAD + 255) / 256;
    int gagg = NNODES / 8;            // 8 nodes/block (2 per wave)

    // layer 1
    k_mfma_gemm<float><<<gHid, 256, 0, stream>>>(x, w1t, nullptr, xh_h, nullptr,
                                                 NNODES, 128, HHD, HHD);
    k_alpha<<<ga, 256, 0, stream>>>(xh_h, a1s, a1d, as_, ad_);
    k_agg<<<gagg, 256, 0, stream>>>(xh_h, as_, ad_, row_ptr, esrc, b1, hbuf_h);

    // layer 2
    k_mfma_gemm<_Float16><<<gHid, 256, 0, stream>>>(hbuf_h, w2t, nullptr, xh_h, nullptr,
                                                    NNODES, HHD, HHD, HHD);
    k_alpha<<<ga, 256, 0, stream>>>(xh_h, a2s, a2d, as_, ad_);
    k_agg<<<gagg, 256, 0, stream>>>(xh_h, as_, ad_, row_ptr, esrc, b2, hbuf_h);

    // classifier
    k_mfma_gemm<_Float16><<<gCls, 256, 0, stream>>>(hbuf_h, wct, bc, nullptr, out,
                                                    NNODES, HHD, NCLS, NCLS);
}

// Round 10
// 336.445 us; speedup vs baseline: 1.4296x; 1.0385x over previous
//
#include <hip/hip_runtime.h>
#include <math.h>

#define NNODES 50000
#define NEDGES 800000
#define NTOT   850000   // edges + self-loops
#define NHEAD  8
#define HDIM   32
#define HHD    256      // NHEAD*HDIM
#define NCLS   40
#define NEG_SLOPE 0.2f

typedef _Float16 half4 __attribute__((ext_vector_type(4)));
typedef _Float16 half8 __attribute__((ext_vector_type(8)));
typedef float f32x16 __attribute__((ext_vector_type(16)));
typedef unsigned short u16;

// ---------------- CSR build ----------------

__global__ void k_init_counts(int* __restrict__ counts) {
    int i = blockIdx.x * 256 + threadIdx.x;
    if (i < NNODES) counts[i] = 1;   // self-loop
}

__global__ void k_count(const int* __restrict__ ei, int* __restrict__ counts) {
    int i = blockIdx.x * 256 + threadIdx.x;
    if (i < NEDGES) atomicAdd(&counts[ei[NEDGES + i]], 1);  // dst row
}

__global__ __launch_bounds__(256) void k_scan1(const int* __restrict__ counts,
                                               int* __restrict__ partial,
                                               int* __restrict__ bsums) {
    __shared__ int lds[256];
    int t = threadIdx.x;
    int i = blockIdx.x * 256 + t;
    int v = (i < NNODES) ? counts[i] : 0;
    lds[t] = v;
    __syncthreads();
    for (int off = 1; off < 256; off <<= 1) {
        int add = (t >= off) ? lds[t - off] : 0;
        __syncthreads();
        lds[t] += add;
        __syncthreads();
    }
    if (i < NNODES) partial[i] = lds[t] - v;   // exclusive within block
    if (t == 255) bsums[blockIdx.x] = lds[255];
}

__global__ __launch_bounds__(256) void k_scan2(const int* __restrict__ bsums,
                                               int* __restrict__ boff, int nb) {
    __shared__ int lds[256];
    int t = threadIdx.x;
    int v = (t < nb) ? bsums[t] : 0;
    lds[t] = v;
    __syncthreads();
    for (int off = 1; off < 256; off <<= 1) {
        int add = (t >= off) ? lds[t - off] : 0;
        __syncthreads();
        lds[t] += add;
        __syncthreads();
    }
    if (t < nb) boff[t] = lds[t] - v;
}

__global__ void k_scan3(int* __restrict__ row_ptr, const int* __restrict__ boff,
                        int* __restrict__ cursor) {
    int i = blockIdx.x * 256 + threadIdx.x;
    if (i < NNODES) {
        int r = row_ptr[i] + boff[blockIdx.x];
        row_ptr[i] = r;
        cursor[i] = r;
    }
    if (i == 0) row_ptr[NNODES] = NTOT;
}

// fused: regular edges + self-loops
__global__ void k_scatter(const int* __restrict__ ei, int* __restrict__ cursor,
                          int* __restrict__ esrc) {
    int i = blockIdx.x * 256 + threadIdx.x;
    if (i < NEDGES) {
        int s = ei[i];
        int d = ei[NEDGES + i];
        int pos = atomicAdd(&cursor[d], 1);
        esrc[pos] = s;
    } else if (i < NTOT) {
        int n = i - NEDGES;
        int pos = atomicAdd(&cursor[n], 1);
        esrc[pos] = n;
    }
}

// ---------------- weight prep: all three weights, MFMA fragment layout -----
// frag layout: frag f of a weight = (fn, fk); lane l holds 8 halves of
// col n = fn*32+(l&31), rows k = fk*16+((l>>5)<<3)+j. One wave half8 load of a
// frag is 1 KB contiguous -> coalesced B reads in GEMM.
__global__ void k_prep_all(const float* __restrict__ W1, const float* __restrict__ W2,
                           const float* __restrict__ Wc,
                           _Float16* __restrict__ w1t, _Float16* __restrict__ w2t,
                           _Float16* __restrict__ wct) {
    int gid = blockIdx.x * 256 + threadIdx.x;   // 256 frags x 64 lanes
    if (gid >= 256 * 64) return;
    int frag = gid >> 6, l = gid & 63;
    const float* W; _Float16* Wt; int K, Nc, fkn, fbase;
    if (frag < 64)       { W = W1; Wt = w1t; K = 128; Nc = 256; fkn = 8;  fbase = 0; }
    else if (frag < 192) { W = W2; Wt = w2t; K = 256; Nc = 256; fkn = 16; fbase = 64; }
    else                 { W = Wc; Wt = wct; K = 256; Nc = 40;  fkn = 16; fbase = 192; }
    int f = frag - fbase;
    int fn = f / fkn, fk = f - fn * fkn;
    int n = fn * 32 + (l & 31);
    int k = fk * 16 + ((l >> 5) << 3);
    half8 v;
    #pragma unroll
    for (int j = 0; j < 8; ++j)
        v[j] = (n < Nc) ? (_Float16)W[(size_t)(k + j) * Nc + n] : (_Float16)0.f;
    *reinterpret_cast<half8*>(Wt + ((size_t)f * 64 + l) * 8) = v;
}

// ---------------- MFMA f16 GEMM (A: fp32 or fp16; B: fragment-packed) ------
// FUSE_ALPHA: epilogue also computes alpha_s/alpha_d for this block's
// 128 rows x 4 heads (head = col>>5; one 128-col block = heads bIdx.x*4..+3)
// via an LDS-staged C tile. Removes the separate k_alpha pass.
#define TBM 128
#define TBN 128
#define TBK 32
#define APAD 34   // 68 B row stride = 17 banks (odd) -> conflict-free b128

template <typename AT, bool FUSE_ALPHA>
__global__ __launch_bounds__(256) void k_mfma_gemm(
    const AT* __restrict__ A,
    const _Float16* __restrict__ Wt,   // fragment-packed
    const float* __restrict__ bias,
    _Float16* __restrict__ Ch,
    float* __restrict__ Cf,
    const float* __restrict__ a_src,   // [8][32] (FUSE_ALPHA)
    const float* __restrict__ a_dst,
    float* __restrict__ alpha_s,       // [N][8]
    float* __restrict__ alpha_d,
    int M, int K, int NcReal, int ldc)
{
    constexpr bool A_IS_F32 = sizeof(AT) == 4;
    constexpr int CT_ROWS = FUSE_ALPHA ? TBM : 1;
    __shared__ _Float16 Ah[TBM][APAD];
    __shared__ _Float16 Ct[CT_ROWS][TBN + 4];
    int t = threadIdx.x;
    int lane = t & 63;
    int wid = t >> 6;
    int wr = wid >> 1, wc = wid & 1;            // 2x2 wave grid
    int rowBase = blockIdx.y * TBM;
    int colBase = blockIdx.x * TBN;

    int arow = t >> 1;
    int akoff = (t & 1) * 16;
    bool arow_ok = (rowBase + arow) < M;
    const AT* aptr = A + (size_t)(rowBase + arow) * K + akoff;

    int fkn = K >> 4;   // frags per n-tile row
    size_t bbase[2];
    #pragma unroll
    for (int ct = 0; ct < 2; ++ct) {
        int fn = blockIdx.x * 4 + wc * 2 + ct;
        bbase[ct] = ((size_t)fn * fkn) * 512 + (size_t)lane * 8;
    }

    f32x16 acc[2][2];
    #pragma unroll
    for (int i = 0; i < 2; ++i)
        #pragma unroll
        for (int j = 0; j < 2; ++j)
            #pragma unroll
            for (int r = 0; r < 16; ++r) acc[i][j][r] = 0.f;

    float4 aregf[4];
    half8  aregh[2];
    auto load_a = [&](const AT* ap) {
        if constexpr (A_IS_F32) {
            #pragma unroll
            for (int i = 0; i < 4; ++i)
                aregf[i] = arow_ok ? *reinterpret_cast<const float4*>((const float*)ap + i * 4)
                                   : float4{0.f, 0.f, 0.f, 0.f};
        } else {
            #pragma unroll
            for (int i = 0; i < 2; ++i)
                aregh[i] = arow_ok ? *reinterpret_cast<const half8*>((const _Float16*)ap + i * 8)
                                   : half8{0, 0, 0, 0, 0, 0, 0, 0};
        }
    };
    load_a(aptr);

    for (int k0 = 0; k0 < K; k0 += TBK) {
        if constexpr (A_IS_F32) {
            half8 h0, h1;
            #pragma unroll
            for (int c = 0; c < 4; ++c) {
                float4 v = aregf[c];
                if (c < 2) {
                    h0[c * 4 + 0] = (_Float16)v.x; h0[c * 4 + 1] = (_Float16)v.y;
                    h0[c * 4 + 2] = (_Float16)v.z; h0[c * 4 + 3] = (_Float16)v.w;
                } else {
                    h1[(c - 2) * 4 + 0] = (_Float16)v.x; h1[(c - 2) * 4 + 1] = (_Float16)v.y;
                    h1[(c - 2) * 4 + 2] = (_Float16)v.z; h1[(c - 2) * 4 + 3] = (_Float16)v.w;
                }
            }
            *reinterpret_cast<half8*>(&Ah[arow][akoff])     = h0;
            *reinterpret_cast<half8*>(&Ah[arow][akoff + 8]) = h1;
        } else {
            *reinterpret_cast<half8*>(&Ah[arow][akoff])     = aregh[0];
            *reinterpret_cast<half8*>(&Ah[arow][akoff + 8]) = aregh[1];
        }
        __syncthreads();
        if (k0 + TBK < K) load_a(aptr + k0 + TBK);
        #pragma unroll
        for (int sub = 0; sub < 2; ++sub) {
            int kfo = sub * 16 + (lane >> 5) * 8;
            half8 ah[2];
            #pragma unroll
            for (int rt = 0; rt < 2; ++rt) {
                int r = wr * 64 + rt * 32 + (lane & 31);
                ah[rt] = *reinterpret_cast<const half8*>(&Ah[r][kfo]);
            }
            half8 bh[2];
            int fidx = (k0 >> 4) + sub;            // fragment k index
            #pragma unroll
            for (int ct = 0; ct < 2; ++ct)
                bh[ct] = *reinterpret_cast<const half8*>(Wt + bbase[ct] + (size_t)fidx * 512);
            #pragma unroll
            for (int rt = 0; rt < 2; ++rt)
                #pragma unroll
                for (int ct = 0; ct < 2; ++ct)
                    acc[rt][ct] = __builtin_amdgcn_mfma_f32_32x32x16_f16(
                        ah[rt], bh[ct], acc[rt][ct], 0, 0, 0);
        }
        __syncthreads();
    }

    // ---- epilogue: C/D layout col=lane&31, row=(r&3)+8*(r>>2)+4*(lane>>5) ----
    #pragma unroll
    for (int rt = 0; rt < 2; ++rt)
        #pragma unroll
        for (int ct = 0; ct < 2; ++ct) {
            int lcol = wc * 64 + ct * 32 + (lane & 31);
            int col = colBase + lcol;
            #pragma unroll
            for (int r = 0; r < 16; ++r) {
                int lrow = wr * 64 + rt * 32 + (r & 3) + 8 * (r >> 2) + 4 * (lane >> 5);
                int row = rowBase + lrow;
                float v = acc[rt][ct][r];
                _Float16 hv = (_Float16)v;
                if constexpr (FUSE_ALPHA) Ct[lrow][lcol] = hv;
                if (row >= M) continue;
                if (Ch) {
                    Ch[(size_t)row * ldc + col] = hv;
                } else if (col < NcReal) {
                    Cf[(size_t)row * ldc + col] = v + bias[col];
                }
            }
        }

    if constexpr (FUSE_ALPHA) {
        __syncthreads();
        // 128 rows x 4 heads = 512 (row, head) pairs; 2 per thread
        #pragma unroll
        for (int idx = t; idx < TBM * 4; idx += 256) {
            int lrow = idx >> 2, hoff = idx & 3;
            int grow = rowBase + lrow;
            if (grow < M) {
                int h = blockIdx.x * 4 + hoff;
                const float* as4 = a_src + h * HDIM;
                const float* ad4 = a_dst + h * HDIM;
                float ss = 0.f, sd = 0.f;
                #pragma unroll
                for (int j = 0; j < HDIM; ++j) {
                    float v = (float)Ct[lrow][hoff * 32 + j];
                    ss += v * as4[j];
                    sd += v * ad4[j];
                }
                alpha_s[grow * NHEAD + h] = ss;
                alpha_d[grow * NHEAD + h] = sd;
            }
        }
    }
}

// ---------------- GAT aggregation: fused single-pass softmax + gather ------
// 2 nodes per wave; lane l in [0,32) covers dims [8l, 8l+8) via one half8.
// No max-subtraction: e is a small-scale dot (|e| << 80), exp cannot overflow.
// Manual 4-way unroll for memory-level parallelism (4 gathers in flight).
__global__ __launch_bounds__(256) void k_agg(const _Float16* __restrict__ xh,
                                             const float* __restrict__ alpha_s,
                                             const float* __restrict__ alpha_d,
                                             const int* __restrict__ row_ptr,
                                             const int* __restrict__ esrc,
                                             const float* __restrict__ bias,
                                             _Float16* __restrict__ out) {
    int wave = blockIdx.x * 4 + (threadIdx.x >> 6);
    int node = wave * 2 + ((threadIdx.x & 63) >> 5);
    if (node >= NNODES) return;
    int l = threadIdx.x & 31;        // dim chunk [8l, 8l+8)
    int h = l >> 2;                  // head of this chunk
    int beg = row_ptr[node], end = row_ptr[node + 1];
    float ad = alpha_d[node * NHEAD + h];
    float acc[8] = {};
    float ssum = 0.f;
    int i = beg;
    for (; i + 3 < end; i += 4) {
        int s0 = esrc[i], s1 = esrc[i + 1], s2 = esrc[i + 2], s3 = esrc[i + 3];
        float e0 = alpha_s[s0 * NHEAD + h] + ad;
        float e1 = alpha_s[s1 * NHEAD + h] + ad;
        float e2 = alpha_s[s2 * NHEAD + h] + ad;
        float e3 = alpha_s[s3 * NHEAD + h] + ad;
        half8 v0 = *reinterpret_cast<const half8*>(xh + (size_t)s0 * HHD + l * 8);
        half8 v1 = *reinterpret_cast<const half8*>(xh + (size_t)s1 * HHD + l * 8);
        half8 v2 = *reinterpret_cast<const half8*>(xh + (size_t)s2 * HHD + l * 8);
        half8 v3 = *reinterpret_cast<const half8*>(xh + (size_t)s3 * HHD + l * 8);
        e0 = (e0 > 0.f) ? e0 : NEG_SLOPE * e0;
        e1 = (e1 > 0.f) ? e1 : NEG_SLOPE * e1;
        e2 = (e2 > 0.f) ? e2 : NEG_SLOPE * e2;
        e3 = (e3 > 0.f) ? e3 : NEG_SLOPE * e3;
        float p0 = __expf(e0), p1 = __expf(e1), p2 = __expf(e2), p3 = __expf(e3);
        ssum += (p0 + p1) + (p2 + p3);
        #pragma unroll
        for (int d = 0; d < 8; ++d)
            acc[d] += p0 * (float)v0[d] + p1 * (float)v1[d] +
                      p2 * (float)v2[d] + p3 * (float)v3[d];
    }
    for (; i < end; ++i) {
        int s0 = esrc[i];
        float e0 = alpha_s[s0 * NHEAD + h] + ad;
        half8 v0 = *reinterpret_cast<const half8*>(xh + (size_t)s0 * HHD + l * 8);
        e0 = (e0 > 0.f) ? e0 : NEG_SLOPE * e0;
        float p0 = __expf(e0);
        ssum += p0;
        #pragma unroll
        for (int d = 0; d < 8; ++d)
            acc[d] += p0 * (float)v0[d];
    }
    float inv = 1.f / ssum;
    float4 b0 = *reinterpret_cast<const float4*>(bias + l * 8);
    float4 b1 = *reinterpret_cast<const float4*>(bias + l * 8 + 4);
    float bb[8] = {b0.x, b0.y, b0.z, b0.w, b1.x, b1.y, b1.z, b1.w};
    half8 r;
    #pragma unroll
    for (int d = 0; d < 8; ++d)
        r[d] = (_Float16)fmaxf(acc[d] * inv + bb[d], 0.f);
    *reinterpret_cast<half8*>(out + (size_t)node * HHD + l * 8) = r;
}

// ---------------- launch ----------------

extern "C" void kernel_launch(void* const* d_in, const int* in_sizes, int n_in,
                              void* d_out, int out_size, void* d_ws, size_t ws_size,
                              hipStream_t stream) {
    const float* x   = (const float*)d_in[0];
    const int*   ei  = (const int*)  d_in[1];
    const float* W1  = (const float*)d_in[2];
    const float* a1s = (const float*)d_in[3];
    const float* a1d = (const float*)d_in[4];
    const float* b1  = (const float*)d_in[5];
    const float* W2  = (const float*)d_in[6];
    const float* a2s = (const float*)d_in[7];
    const float* a2d = (const float*)d_in[8];
    const float* b2  = (const float*)d_in[9];
    const float* Wc  = (const float*)d_in[10];
    const float* bc  = (const float*)d_in[11];
    float* out = (float*)d_out;

    char* ws = (char*)d_ws;
    size_t off = 0;
    auto alloc = [&](size_t bytes) -> void* {
        void* p = ws + off;
        off += (bytes + 255) & ~(size_t)255;
        return p;
    };
    _Float16* xh_h   = (_Float16*)alloc((size_t)NNODES * HHD * 2);
    _Float16* hbuf_h = (_Float16*)alloc((size_t)NNODES * HHD * 2);
    float* as_   = (float*)alloc((size_t)NNODES * NHEAD * 4);
    float* ad_   = (float*)alloc((size_t)NNODES * NHEAD * 4);
    int* counts  = (int*)alloc((size_t)NNODES * 4);
    int* row_ptr = (int*)alloc((size_t)(NNODES + 1) * 4);
    int* cursor  = (int*)alloc((size_t)NNODES * 4);
    int* esrc    = (int*)alloc((size_t)NTOT * 4);
    int* bsums   = (int*)alloc(256 * 4);
    int* boff    = (int*)alloc(256 * 4);
    _Float16* w1t = (_Float16*)alloc((size_t)64 * 64 * 8 * 2);    // 64 frags
    _Float16* w2t = (_Float16*)alloc((size_t)128 * 64 * 8 * 2);   // 128 frags
    _Float16* wct = (_Float16*)alloc((size_t)64 * 64 * 8 * 2);    // 64 frags
    (void)ws_size; (void)in_sizes; (void)n_in; (void)out_size;

    int gn = (NNODES + 255) / 256;
    int ge = (NEDGES + 255) / 256;
    int gt = (NTOT + 255) / 256;

    // CSR build (same graph for both layers)
    k_init_counts<<<gn, 256, 0, stream>>>(counts);
    k_count<<<ge, 256, 0, stream>>>(ei, counts);
    k_scan1<<<gn, 256, 0, stream>>>(counts, row_ptr, bsums);
    k_scan2<<<1, 256, 0, stream>>>(bsums, boff, gn);
    k_scan3<<<gn, 256, 0, stream>>>(row_ptr, boff, cursor);
    k_scatter<<<gt, 256, 0, stream>>>(ei, cursor, esrc);

    // weight prep (fragment pack, all three)
    k_prep_all<<<64, 256, 0, stream>>>(W1, W2, Wc, w1t, w2t, wct);

    dim3 gHid(HHD / TBN, (NNODES + TBM - 1) / TBM);   // (2, 391)
    dim3 gCls(1, (NNODES + TBM - 1) / TBM);           // (1, 391)
    int gagg = NNODES / 8;            // 8 nodes/block (2 per wave)

    // layer 1 (GEMM + fused alpha)
    k_mfma_gemm<float, true><<<gHid, 256, 0, stream>>>(
        x, w1t, nullptr, xh_h, nullptr, a1s, a1d, as_, ad_, NNODES, 128, HHD, HHD);
    k_agg<<<gagg, 256, 0, stream>>>(xh_h, as_, ad_, row_ptr, esrc, b1, hbuf_h);

    // layer 2 (GEMM + fused alpha)
    k_mfma_gemm<_Float16, true><<<gHid, 256, 0, stream>>>(
        hbuf_h, w2t, nullptr, xh_h, nullptr, a2s, a2d, as_, ad_, NNODES, HHD, HHD, HHD);
    k_agg<<<gagg, 256, 0, stream>>>(xh_h, as_, ad_, row_ptr, esrc, b2, hbuf_h);

    // classifier
    k_mfma_gemm<_Float16, false><<<gCls, 256, 0, stream>>>(
        hbuf_h, wct, bc, nullptr, out, nullptr, nullptr, nullptr, nullptr,
        NNODES, HHD, NCLS, NCLS);
}